// Round 1
// baseline (3368.628 us; speedup 1.0000x reference)
//
#include <hip/hip_runtime.h>

#define BB 32
#define TT 2048
#define CC 64
#define GN_EPS (1e-5f * 64.f)

__device__ __forceinline__ float wave_sum(float p) {
#pragma unroll
  for (int m = 32; m >= 1; m >>= 1) p += __shfl_xor(p, m, 64);
  return p;
}

__device__ __forceinline__ float tanh_f(float x) {
  x = fminf(fmaxf(x, -10.f), 10.f);
  const float e = __expf(2.f * x);
  return (e - 1.f) / (e + 1.f);
}

__device__ __forceinline__ float dot64(const float* __restrict__ shv, const float* __restrict__ wrow) {
  const float4* w4 = reinterpret_cast<const float4*>(wrow);
  const float4* s4 = reinterpret_cast<const float4*>(shv);
  float acc = 0.f;
#pragma unroll
  for (int c = 0; c < 16; ++c) {
    const float4 w = w4[c];
    const float4 s = s4[c];
    acc = fmaf(w.x, s.x, acc);
    acc = fmaf(w.y, s.y, acc);
    acc = fmaf(w.z, s.z, acc);
    acc = fmaf(w.w, s.w, acc);
  }
  return acc;
}

// One 64-thread block (one wave) per token. thread j = channel j.
__global__ __launch_bounds__(64) void prep_kernel(
    const float* __restrict__ x,
    const float* __restrict__ tm_x, const float* __restrict__ tm_w, const float* __restrict__ tm_k,
    const float* __restrict__ tm_v, const float* __restrict__ tm_r, const float* __restrict__ tm_g,
    const float* __restrict__ maa_w1, const float* __restrict__ maa_w2,
    const float* __restrict__ t_decay, const float* __restrict__ dec_w1, const float* __restrict__ dec_w2,
    const float* __restrict__ u,
    const float* __restrict__ Wr, const float* __restrict__ Wk, const float* __restrict__ Wv,
    const float* __restrict__ Wg,
    float* __restrict__ r_o, float* __restrict__ k_o, float* __restrict__ v_o,
    float* __restrict__ dec_o, float* __restrict__ g_o, float* __restrict__ ct_o)
{
  const int bt = blockIdx.x;
  const int t = bt & (TT - 1);
  const int j = threadIdx.x;
  __shared__ alignas(16) float sxxx[CC];
  __shared__ alignas(16) float sa[160];
  __shared__ alignas(16) float sxw[CC];
  __shared__ alignas(16) float sxk[CC];
  __shared__ alignas(16) float sxv[CC];
  __shared__ alignas(16) float sxr[CC];
  __shared__ alignas(16) float sxg[CC];
  __shared__ alignas(16) float shh[CC];

  const size_t off = (size_t)bt * CC;
  const float xc = x[off + j];
  const float xp = (t > 0) ? x[off - CC + j] : 0.f;
  const float xx = xp - xc;  // x[t-1] - x[t]
  sxxx[j] = fmaf(xx, tm_x[j], xc);
  __syncthreads();

  // a = tanh(xxx @ maa_w1) : thread j computes columns j, j+64 (and j+128 if j<32)
  float a0 = 0.f, a1 = 0.f, a2 = 0.f;
#pragma unroll 8
  for (int c = 0; c < CC; ++c) {
    const float xv_ = sxxx[c];
    const float* wr = maa_w1 + c * 160;
    a0 = fmaf(xv_, wr[j], a0);
    a1 = fmaf(xv_, wr[j + 64], a1);
    if (j < 32) a2 = fmaf(xv_, wr[j + 128], a2);
  }
  sa[j] = tanh_f(a0);
  sa[j + 64] = tanh_f(a1);
  if (j < 32) sa[j + 128] = tanh_f(a2);
  __syncthreads();

  // m[f][j] = sum_q a[f*32+q] * maa_w2[f][q][j]
  float m0 = 0.f, m1 = 0.f, m2 = 0.f, m3 = 0.f, m4 = 0.f;
#pragma unroll 8
  for (int q = 0; q < 32; ++q) {
    m0 = fmaf(sa[q],       maa_w2[(0 * 32 + q) * CC + j], m0);
    m1 = fmaf(sa[32 + q],  maa_w2[(1 * 32 + q) * CC + j], m1);
    m2 = fmaf(sa[64 + q],  maa_w2[(2 * 32 + q) * CC + j], m2);
    m3 = fmaf(sa[96 + q],  maa_w2[(3 * 32 + q) * CC + j], m3);
    m4 = fmaf(sa[128 + q], maa_w2[(4 * 32 + q) * CC + j], m4);
  }
  sxw[j] = fmaf(xx, tm_w[j] + m0, xc);
  sxk[j] = fmaf(xx, tm_k[j] + m1, xc);
  sxv[j] = fmaf(xx, tm_v[j] + m2, xc);
  sxr[j] = fmaf(xx, tm_r[j] + m3, xc);
  sxg[j] = fmaf(xx, tm_g[j] + m4, xc);
  __syncthreads();

  // projections: out[j] = sum_c xin[c] * W[j][c]   (x @ W.T)
  const float rj = dot64(sxr, Wr + j * CC);
  const float kj = dot64(sxk, Wk + j * CC);
  const float vj = dot64(sxv, Wv + j * CC);
  float gj = dot64(sxg, Wg + j * CC);
  gj = gj / (1.f + __expf(-gj));  // silu

  // h[j] = tanh(sum_c xw[c] * dec_w1[c][j])
  float ha = 0.f;
#pragma unroll 8
  for (int c = 0; c < CC; ++c) ha = fmaf(sxw[c], dec_w1[c * CC + j], ha);
  shh[j] = tanh_f(ha);
  __syncthreads();

  // w[j] = t_decay[j] + sum_q h[q] * dec_w2[q][j];  dec = exp(-exp(w))
  float wv_ = t_decay[j];
#pragma unroll 8
  for (int q = 0; q < CC; ++q) wv_ = fmaf(shh[q], dec_w2[q * CC + j], wv_);
  const float dj = __expf(-__expf(wv_));

  // ct = sum_i r_i * u_i * k_i  (folds the bonus term: y_j = sum_i r_i S_ij + ct * v_j)
  const float ct = wave_sum(rj * u[j] * kj);

  r_o[off + j] = rj;
  k_o[off + j] = kj;
  v_o[off + j] = vj;
  dec_o[off + j] = dj;
  g_o[off + j] = gj;
  if (j == 0) ct_o[bt] = ct;
}

// WKV6 scan. One 64-thread block per (batch b, output column j).
// lane i holds S[i][j]; per step: y_j = sum_i r_i*S_ij + ct*v_j ; S_ij = S_ij*d_i + k_i*v_j
__global__ __launch_bounds__(64) void scan_kernel(
    const float* __restrict__ rb, const float* __restrict__ kb, const float* __restrict__ db,
    const float* __restrict__ vb, const float* __restrict__ cb, float* __restrict__ yb)
{
  const int bid = blockIdx.x;
  const int b = bid >> 6;
  const int j = bid & 63;
  const int i = threadIdx.x;
  const size_t base = (size_t)b * TT * CC;
  const float* rp = rb + base + i;
  const float* kp = kb + base + i;
  const float* dp = db + base + i;
  const float* vp = vb + base + j;       // uniform across lanes
  const float* cp = cb + (size_t)b * TT; // uniform across lanes
  float* yp = yb + base + j;

  float S = 0.f;
  float r0 = rp[0], k0 = kp[0], d0 = dp[0], v0 = vp[0], c0 = cp[0];
#pragma unroll 2
  for (int t = 0; t < TT; ++t) {
    const int tn = (t + 1 < TT) ? (t + 1) : (TT - 1);
    const size_t on = (size_t)tn * CC;
    const float r1 = rp[on];
    const float k1 = kp[on];
    const float d1 = dp[on];
    const float v1 = vp[on];
    const float c1 = cp[tn];

    const float kv = k0 * v0;
    float p = r0 * S;          // uses OLD state
    S = fmaf(S, d0, kv);       // decay + rank-1 update
    p = wave_sum(p);
    if (i == 0) yp[(size_t)t * CC] = fmaf(c0, v0, p);

    r0 = r1; k0 = k1; d0 = d1; v0 = v1; c0 = c1;
  }
}

// GroupNorm(64) + *g + @Wo.T, in-place on d_out (reads y, writes final output).
__global__ __launch_bounds__(64) void post_kernel(
    const float* __restrict__ g_i, const float* __restrict__ ln_w, const float* __restrict__ ln_b,
    const float* __restrict__ Wo, float* __restrict__ out)
{
  const int bt = blockIdx.x;
  const int j = threadIdx.x;
  const size_t off = (size_t)bt * CC;
  const float y = out[off + j];
  const float s1 = wave_sum(y);
  const float s2 = wave_sum(y * y);
  const float mu = s1 * (1.f / CC);
  const float var = s2 * (1.f / CC) - mu * mu;
  const float z = (y - mu) * rsqrtf(var + GN_EPS) * ln_w[j] + ln_b[j];
  __shared__ alignas(16) float sz[CC];
  sz[j] = z * g_i[off + j];
  __syncthreads();
  out[off + j] = dot64(sz, Wo + j * CC);
}

extern "C" void kernel_launch(void* const* d_in, const int* in_sizes, int n_in,
                              void* d_out, int out_size, void* d_ws, size_t ws_size,
                              hipStream_t stream) {
  const float* x       = (const float*)d_in[0];
  const float* tm_x    = (const float*)d_in[1];
  const float* tm_w    = (const float*)d_in[2];
  const float* tm_k    = (const float*)d_in[3];
  const float* tm_v    = (const float*)d_in[4];
  const float* tm_r    = (const float*)d_in[5];
  const float* tm_g    = (const float*)d_in[6];
  const float* maa_w1  = (const float*)d_in[7];
  const float* maa_w2  = (const float*)d_in[8];
  const float* t_decay = (const float*)d_in[9];
  const float* dec_w1  = (const float*)d_in[10];
  const float* dec_w2  = (const float*)d_in[11];
  const float* u       = (const float*)d_in[12];
  const float* Wr      = (const float*)d_in[13];
  const float* Wk      = (const float*)d_in[14];
  const float* Wv      = (const float*)d_in[15];
  const float* Wg      = (const float*)d_in[16];
  const float* Wo      = (const float*)d_in[17];
  const float* ln_w    = (const float*)d_in[18];
  const float* ln_b    = (const float*)d_in[19];

  const size_t M = (size_t)BB * TT * CC;
  float* ws   = (float*)d_ws;
  float* r_o  = ws;
  float* k_o  = ws + M;
  float* v_o  = ws + 2 * M;
  float* dc_o = ws + 3 * M;
  float* g_o  = ws + 4 * M;
  float* ct_o = ws + 5 * M;  // B*T scalars
  float* out  = (float*)d_out;

  prep_kernel<<<BB * TT, 64, 0, stream>>>(
      x, tm_x, tm_w, tm_k, tm_v, tm_r, tm_g, maa_w1, maa_w2, t_decay, dec_w1, dec_w2, u,
      Wr, Wk, Wv, Wg, r_o, k_o, v_o, dc_o, g_o, ct_o);

  scan_kernel<<<BB * CC, 64, 0, stream>>>(r_o, k_o, dc_o, v_o, ct_o, out);

  post_kernel<<<BB * TT, 64, 0, stream>>>(g_o, ln_w, ln_b, Wo, out);
}

// Round 3
// 730.229 us; speedup vs baseline: 4.6131x; 4.6131x over previous
//
#include <hip/hip_runtime.h>

#define BB 32
#define TT 2048
#define CC 64
#define BT (BB * TT)
#define GN_EPS (1e-5f * 64.f)

// ---- cross-lane helpers --------------------------------------------------
__device__ __forceinline__ float rl(float v, int lane) {
  return __uint_as_float(__builtin_amdgcn_readlane(__float_as_uint(v), lane));
}
// x + dpp_moved(x): one level of Hillis-Steele; invalid source lanes read 0.
template <int CTRL>
__device__ __forceinline__ float dppadd(float x) {
  return x + __int_as_float(__builtin_amdgcn_update_dpp(
                 0, __float_as_int(x), CTRL, 0xf, 0xf, true));
}
// Full wave64 sum: row_shr 1,2,4,8 then row_bcast:15, row_bcast:31 -> lane 63
// holds the total; broadcast with readlane.
__device__ __forceinline__ float wave_red_sum(float x) {
  x = dppadd<0x111>(x);  // row_shr:1
  x = dppadd<0x112>(x);  // row_shr:2
  x = dppadd<0x114>(x);  // row_shr:4
  x = dppadd<0x118>(x);  // row_shr:8
  x = dppadd<0x142>(x);  // row_bcast:15
  x = dppadd<0x143>(x);  // row_bcast:31
  return __uint_as_float(__builtin_amdgcn_readlane(__float_as_uint(x), 63));
}
__device__ __forceinline__ float tanh_f(float x) {
  x = fminf(fmaxf(x, -10.f), 10.f);
  const float e = __expf(2.f * x);
  return (e - 1.f) / (e + 1.f);
}

// ---- mix: token-shift + maa mixing -> 5 shifted streams ------------------
// 512 thr = 8 waves; each wave does 4 tokens; block = 32 tokens.
__global__ __launch_bounds__(512, 2) void mix_kernel(
    const float* __restrict__ x,
    const float* __restrict__ tm_x, const float* __restrict__ tm_w, const float* __restrict__ tm_k,
    const float* __restrict__ tm_v, const float* __restrict__ tm_r, const float* __restrict__ tm_g,
    const float* __restrict__ maa_w1, const float* __restrict__ maa_w2,
    float* __restrict__ xw_o, float* __restrict__ xk_o, float* __restrict__ xv_o,
    float* __restrict__ xr_o, float* __restrict__ xg_o)
{
  __shared__ float4 w1L[4096];  // {w1[c][j], w1[c][64+j], w1[c][128+j] (j<32), 0}
  __shared__ float4 w2a[2048];  // {w2[f=0..3][q][j]}
  __shared__ float  w2b[2048];  // w2[f=4][q][j]
  const int tid = threadIdx.x;
  for (int idx = tid; idx < 4096; idx += 512) {
    const int c = idx >> 6, jj = idx & 63;
    const float v0 = maa_w1[c * 160 + jj];
    const float v1 = maa_w1[c * 160 + 64 + jj];
    const float v2 = (jj < 32) ? maa_w1[c * 160 + 128 + jj] : 0.f;
    w1L[idx] = make_float4(v0, v1, v2, 0.f);
  }
  for (int idx = tid; idx < 2048; idx += 512) {
    const int q = idx >> 6, jj = idx & 63;
    w2a[idx] = make_float4(maa_w2[q * 64 + jj], maa_w2[(32 + q) * 64 + jj],
                           maa_w2[(64 + q) * 64 + jj], maa_w2[(96 + q) * 64 + jj]);
    w2b[idx] = maa_w2[(128 + q) * 64 + jj];
  }
  __syncthreads();

  const int w = tid >> 6, j = tid & 63;
  const int bt0 = blockIdx.x * 32 + w * 4;
  const float tmx = tm_x[j], tmw = tm_w[j], tmk = tm_k[j],
              tmv = tm_v[j], tmr = tm_r[j], tmg = tm_g[j];

  float xc[4], xx[4], xxx[4];
#pragma unroll
  for (int q = 0; q < 4; ++q) {
    const int bt = bt0 + q;
    const int t = bt & (TT - 1);
    const float cur = x[(size_t)bt * CC + j];
    const float prv = (t != 0) ? x[(size_t)(bt - 1) * CC + j] : 0.f;
    xc[q] = cur;
    xx[q] = prv - cur;
    xxx[q] = fmaf(xx[q], tmx, cur);
  }

  float a0[4] = {0, 0, 0, 0}, a1[4] = {0, 0, 0, 0}, a2[4] = {0, 0, 0, 0};
#pragma unroll
  for (int c = 0; c < 64; ++c) {
    const float4 wv = w1L[c * 64 + j];
#pragma unroll
    for (int q = 0; q < 4; ++q) {
      const float s = rl(xxx[q], c);
      a0[q] = fmaf(s, wv.x, a0[q]);
      a1[q] = fmaf(s, wv.y, a1[q]);
      a2[q] = fmaf(s, wv.z, a2[q]);
    }
  }
#pragma unroll
  for (int q = 0; q < 4; ++q) {
    a0[q] = tanh_f(a0[q]); a1[q] = tanh_f(a1[q]); a2[q] = tanh_f(a2[q]);
  }

  float m0[4] = {0,0,0,0}, m1[4] = {0,0,0,0}, m2[4] = {0,0,0,0},
        m3[4] = {0,0,0,0}, m4[4] = {0,0,0,0};
#pragma unroll
  for (int q2 = 0; q2 < 32; ++q2) {
    const float4 w4 = w2a[q2 * 64 + j];
    const float w5 = w2b[q2 * 64 + j];
#pragma unroll
    for (int q = 0; q < 4; ++q) {
      m0[q] = fmaf(rl(a0[q], q2),      w4.x, m0[q]);
      m1[q] = fmaf(rl(a0[q], 32 + q2), w4.y, m1[q]);
      m2[q] = fmaf(rl(a1[q], q2),      w4.z, m2[q]);
      m3[q] = fmaf(rl(a1[q], 32 + q2), w4.w, m3[q]);
      m4[q] = fmaf(rl(a2[q], q2),      w5,   m4[q]);
    }
  }
#pragma unroll
  for (int q = 0; q < 4; ++q) {
    const size_t o = (size_t)(bt0 + q) * CC + j;
    xw_o[o] = fmaf(xx[q], tmw + m0[q], xc[q]);
    xk_o[o] = fmaf(xx[q], tmk + m1[q], xc[q]);
    xv_o[o] = fmaf(xx[q], tmv + m2[q], xc[q]);
    xr_o[o] = fmaf(xx[q], tmr + m3[q], xc[q]);
    xg_o[o] = fmaf(xx[q], tmg + m4[q], xc[q]);
  }
}

// ---- proj: 4 projections + decay MLP + ct; outputs packed for the scan ---
__global__ __launch_bounds__(512, 2) void proj_kernel(
    const float* __restrict__ xw_i, const float* __restrict__ xk_i, const float* __restrict__ xv_i,
    const float* __restrict__ xr_i, const float* __restrict__ xg_i,
    const float* __restrict__ t_decay, const float* __restrict__ dec_w1,
    const float* __restrict__ dec_w2, const float* __restrict__ u,
    const float* __restrict__ Wr, const float* __restrict__ Wk, const float* __restrict__ Wv,
    const float* __restrict__ Wg,
    float4* __restrict__ rkdc, float* __restrict__ vT, float* __restrict__ g_o)
{
  __shared__ float4 projW[4096];   // {Wr^T, Wk^T, Wv^T, Wg^T}[c][j]
  __shared__ float2 decW[4096];    // {dec_w1[c][j], dec_w2[c][j]}
  __shared__ float vbuf[64][33];   // v transpose staging
  const int tid = threadIdx.x;
  for (int idx = tid; idx < 4096; idx += 512) {
    const int c = idx >> 6, jj = idx & 63;
    projW[idx] = make_float4(Wr[jj * 64 + c], Wk[jj * 64 + c],
                             Wv[jj * 64 + c], Wg[jj * 64 + c]);
    decW[idx] = make_float2(dec_w1[idx], dec_w2[idx]);
  }
  __syncthreads();

  const int w = tid >> 6, j = tid & 63;
  const int bt0 = blockIdx.x * 32 + w * 4;
  const float u_j = u[j], td = t_decay[j];

  float xw[4], xk[4], xv_[4], xr[4], xg[4];
#pragma unroll
  for (int q = 0; q < 4; ++q) {
    const size_t o = (size_t)(bt0 + q) * CC + j;
    xw[q] = xw_i[o]; xk[q] = xk_i[o]; xv_[q] = xv_i[o]; xr[q] = xr_i[o]; xg[q] = xg_i[o];
  }

  float ar[4] = {0,0,0,0}, ak[4] = {0,0,0,0}, av[4] = {0,0,0,0}, ag[4] = {0,0,0,0};
#pragma unroll
  for (int c = 0; c < 64; ++c) {
    const float4 wv = projW[c * 64 + j];
#pragma unroll
    for (int q = 0; q < 4; ++q) {
      ar[q] = fmaf(rl(xr[q], c),  wv.x, ar[q]);
      ak[q] = fmaf(rl(xk[q], c),  wv.y, ak[q]);
      av[q] = fmaf(rl(xv_[q], c), wv.z, av[q]);
      ag[q] = fmaf(rl(xg[q], c),  wv.w, ag[q]);
    }
  }

  float hh[4] = {0,0,0,0};
#pragma unroll
  for (int c = 0; c < 64; ++c) {
    const float dw = decW[c * 64 + j].x;
#pragma unroll
    for (int q = 0; q < 4; ++q) hh[q] = fmaf(rl(xw[q], c), dw, hh[q]);
  }
#pragma unroll
  for (int q = 0; q < 4; ++q) hh[q] = tanh_f(hh[q]);

  float wf[4] = {td, td, td, td};
#pragma unroll
  for (int c = 0; c < 64; ++c) {
    const float dw = decW[c * 64 + j].y;
#pragma unroll
    for (int q = 0; q < 4; ++q) wf[q] = fmaf(rl(hh[q], c), dw, wf[q]);
  }

#pragma unroll
  for (int q = 0; q < 4; ++q) {
    const size_t o = (size_t)(bt0 + q) * CC + j;
    const float dj = __expf(-__expf(wf[q]));
    const float ct = wave_red_sum(ar[q] * u_j * ak[q]);  // sum_i r_i u_i k_i
    rkdc[o] = make_float4(ar[q], ak[q], dj, ct);
    g_o[o] = ag[q] / (1.f + __expf(-ag[q]));  // silu
    vbuf[j][w * 4 + q] = av[q];
  }
  __syncthreads();
  // v transpose: vT[b][j][t], coalesced store
  const int b = blockIdx.x >> 6;
  const int tblk = (blockIdx.x & 63) * 32;
  for (int idx = tid; idx < 2048; idx += 512) {
    const int jj = idx >> 5, tt = idx & 31;
    vT[((size_t)b * CC + jj) * TT + tblk + tt] = vbuf[jj][tt];
  }
}

// ---- WKV6 scan: wave = (b, j); lane i holds S[i][j] ----------------------
__global__ __launch_bounds__(256, 2) void scan_kernel(
    const float4* __restrict__ rkdc, const float* __restrict__ vT, float* __restrict__ yb)
{
  const int blk = blockIdx.x;
  const int b = blk >> 4;
  const int j = ((blk & 15) << 2) + (threadIdx.x >> 6);
  const int i = threadIdx.x & 63;
  const float4* fp = rkdc + (size_t)b * TT * CC + i;  // step: +64 float4 per t
  const float* vp = vT + ((size_t)b * CC + j) * TT;
  float* yp = yb + (size_t)b * TT * CC + j;

  float S = 0.f;
  float4 f0 = fp[0 * 64], f1 = fp[1 * 64], f2 = fp[2 * 64], f3 = fp[3 * 64];
  float4 vvc = *reinterpret_cast<const float4*>(vp);

  for (int t = 0; t < TT; t += 4) {
    const int tv = (t + 4 < TT) ? t + 4 : TT - 4;
    const float4 vvn = *reinterpret_cast<const float4*>(vp + tv);
    // step t+0
    {
      const float p = wave_red_sum(f0.x * S);
      S = fmaf(S, f0.z, f0.y * vvc.x);
      if (i == 0) yp[(size_t)t * CC] = fmaf(f0.w, vvc.x, p);
      int tn = t + 4; if (tn > TT - 1) tn = TT - 1;
      f0 = fp[(size_t)tn * CC];
    }
    // step t+1
    {
      const float p = wave_red_sum(f1.x * S);
      S = fmaf(S, f1.z, f1.y * vvc.y);
      if (i == 0) yp[(size_t)(t + 1) * CC] = fmaf(f1.w, vvc.y, p);
      int tn = t + 5; if (tn > TT - 1) tn = TT - 1;
      f1 = fp[(size_t)tn * CC];
    }
    // step t+2
    {
      const float p = wave_red_sum(f2.x * S);
      S = fmaf(S, f2.z, f2.y * vvc.z);
      if (i == 0) yp[(size_t)(t + 2) * CC] = fmaf(f2.w, vvc.z, p);
      int tn = t + 6; if (tn > TT - 1) tn = TT - 1;
      f2 = fp[(size_t)tn * CC];
    }
    // step t+3
    {
      const float p = wave_red_sum(f3.x * S);
      S = fmaf(S, f3.z, f3.y * vvc.w);
      if (i == 0) yp[(size_t)(t + 3) * CC] = fmaf(f3.w, vvc.w, p);
      int tn = t + 7; if (tn > TT - 1) tn = TT - 1;
      f3 = fp[(size_t)tn * CC];
    }
    vvc = vvn;
  }
}

// ---- post: GroupNorm(64) + *g + @Wo.T, in place on d_out -----------------
__global__ __launch_bounds__(512, 2) void post_kernel(
    const float* __restrict__ g_i, const float* __restrict__ ln_w, const float* __restrict__ ln_b,
    const float* __restrict__ Wo, float* __restrict__ out)
{
  __shared__ float WoT[4096];  // Wo^T[c][j]
  const int tid = threadIdx.x;
  for (int idx = tid; idx < 4096; idx += 512) {
    const int c = idx >> 6, jj = idx & 63;
    WoT[idx] = Wo[jj * 64 + c];
  }
  __syncthreads();
  const int w = tid >> 6, j = tid & 63;
  const int bt0 = blockIdx.x * 32 + w * 4;
  const float lnw = ln_w[j], lnb = ln_b[j];
  float sz[4];
#pragma unroll
  for (int q = 0; q < 4; ++q) {
    const size_t o = (size_t)(bt0 + q) * CC + j;
    const float y = out[o];
    const float s1 = wave_red_sum(y);
    const float s2 = wave_red_sum(y * y);
    const float mu = s1 * (1.f / CC);
    const float var = s2 * (1.f / CC) - mu * mu;
    const float z = (y - mu) * rsqrtf(var + GN_EPS) * lnw + lnb;
    sz[q] = z * g_i[o];
  }
  float acc[4] = {0, 0, 0, 0};
#pragma unroll
  for (int c = 0; c < 64; ++c) {
    const float wv = WoT[c * 64 + j];
#pragma unroll
    for (int q = 0; q < 4; ++q) acc[q] = fmaf(rl(sz[q], c), wv, acc[q]);
  }
#pragma unroll
  for (int q = 0; q < 4; ++q) out[(size_t)(bt0 + q) * CC + j] = acc[q];
}

extern "C" void kernel_launch(void* const* d_in, const int* in_sizes, int n_in,
                              void* d_out, int out_size, void* d_ws, size_t ws_size,
                              hipStream_t stream) {
  const float* x       = (const float*)d_in[0];
  const float* tm_x    = (const float*)d_in[1];
  const float* tm_w    = (const float*)d_in[2];
  const float* tm_k    = (const float*)d_in[3];
  const float* tm_v    = (const float*)d_in[4];
  const float* tm_r    = (const float*)d_in[5];
  const float* tm_g    = (const float*)d_in[6];
  const float* maa_w1  = (const float*)d_in[7];
  const float* maa_w2  = (const float*)d_in[8];
  const float* t_decay = (const float*)d_in[9];
  const float* dec_w1  = (const float*)d_in[10];
  const float* dec_w2  = (const float*)d_in[11];
  const float* u       = (const float*)d_in[12];
  const float* Wr      = (const float*)d_in[13];
  const float* Wk      = (const float*)d_in[14];
  const float* Wv      = (const float*)d_in[15];
  const float* Wg      = (const float*)d_in[16];
  const float* Wo      = (const float*)d_in[17];
  const float* ln_w    = (const float*)d_in[18];
  const float* ln_b    = (const float*)d_in[19];

  const size_t M = (size_t)BT * CC;
  float* ws   = (float*)d_ws;
  float* xk_o = ws;
  float* xv_o = ws + M;
  float* xr_o = ws + 2 * M;
  float* xg_o = ws + 3 * M;
  float* g_o  = ws + 4 * M;
  float* vT   = ws + 5 * M;
  float4* rkdc = (float4*)(ws + 6 * M);  // occupies [6M, 10M) floats
  float* out  = (float*)d_out;           // reused: xw stream -> y -> final

  mix_kernel<<<2048, 512, 0, stream>>>(
      x, tm_x, tm_w, tm_k, tm_v, tm_r, tm_g, maa_w1, maa_w2,
      out /* xw */, xk_o, xv_o, xr_o, xg_o);

  proj_kernel<<<2048, 512, 0, stream>>>(
      out /* xw */, xk_o, xv_o, xr_o, xg_o, t_decay, dec_w1, dec_w2, u,
      Wr, Wk, Wv, Wg, rkdc, vT, g_o);

  scan_kernel<<<512, 256, 0, stream>>>(rkdc, vT, out /* y */);

  post_kernel<<<2048, 512, 0, stream>>>(g_o, ln_w, ln_b, Wo, out);
}